// Round 12
// baseline (148.176 us; speedup 1.0000x reference)
//
#include <hip/hip_runtime.h>
#include <hip/hip_bf16.h>
#include <stdint.h>

#define LL 2048
#define SS 2048
#define HH 8
#define EE 64
#define RSG 512   // global row stride in elements (H*E)

typedef float v4f  __attribute__((ext_vector_type(4)));
typedef float v16f __attribute__((ext_vector_type(16)));
typedef short s4v  __attribute__((ext_vector_type(4)));
typedef short s8v  __attribute__((ext_vector_type(8)));

// fp32 -> bf16 bits, round-to-nearest-even
__device__ __forceinline__ short f2bf(float f) {
    unsigned u = __float_as_uint(f);
    u = (u + 0x7fffu + ((u >> 16) & 1u)) >> 16;
    return (short)u;
}

__device__ __forceinline__ s4v pack4bf(float a, float b, float c, float d) {
    float2 ab = make_float2(a, b), cd = make_float2(c, d);
    __hip_bfloat162 r0 = __float22bfloat162_rn(ab);
    __hip_bfloat162 r1 = __float22bfloat162_rn(cd);
    s4v r;
    __builtin_memcpy(&r, &r0, 4);
    __builtin_memcpy(((char*)&r) + 4, &r1, 4);
    return r;
}

// ---------------- prepass (r11 bandwidth-optimized version, verified) -------
// K image: chunk u = echunk*64 + srow  holds K[srow][8*echunk .. +8) as bf16.
// V image: chunk u = c*64 + e          holds V[perm(c,j)][e], j=0..7, with
//   perm(c,j) = 16*(c>>1) + 4*(c&1) + 8*(j>>2) + (j&3)   (the PV k-permutation)
__global__ __launch_bounds__(256)
void dsattn_prep(const float* __restrict__ kk, const float* __restrict__ vv,
                 short* __restrict__ kimg, short* __restrict__ vimg)
{
    __shared__ short T[32][520];         // 32 rows x 512 bf16 (+8 pad)
    const int t   = threadIdx.x;
    const int blk = blockIdx.x;          // 0..255
    const int isV = blk >> 7;            // 0: K-tensor, 1: V-tensor
    const int b   = (blk & 127) >> 5;
    const int ts  = blk & 31;
    const float* src = (isV ? vv : kk) + ((size_t)b * SS + ts * 64) * RSG;
    short* dimg = isV ? vimg : kimg;

    #pragma unroll 1
    for (int half = 0; half < 2; ++half) {
        const float* hsrc = src + (size_t)(half * 32) * RSG;
        #pragma unroll
        for (int i = 0; i < 16; ++i) {
            int g = i * 256 + t;
            int row = g >> 7, c4 = (g & 127) << 2;
            v4f d = *(const v4f*)(hsrc + (size_t)row * RSG + c4);
            *(s4v*)&T[row][c4] = pack4bf(d[0], d[1], d[2], d[3]);
        }
        __syncthreads();

        if (!isV) {
            const int echunk = t >> 5, srow = t & 31;
            #pragma unroll
            for (int h = 0; h < 8; ++h) {
                s8v ov = *(const s8v*)&T[srow][h * 64 + echunk * 8];
                short* dst = dimg + ((size_t)((b * 8 + h) * 32 + ts)) * 4096
                           + (echunk * 64 + half * 32 + srow) * 8;
                *(s8v*)dst = ov;
            }
        } else {
            const int c = (t >> 6) + half * 4, e = t & 63;
            const int sbase = 16 * (c >> 1) + 4 * (c & 1) - half * 32;
            #pragma unroll
            for (int h = 0; h < 8; ++h) {
                s8v ov;
                #pragma unroll
                for (int j = 0; j < 8; ++j) {
                    int s = sbase + 8 * (j >> 2) + (j & 3);
                    ov[j] = T[s][h * 64 + e];
                }
                short* dst = dimg + ((size_t)((b * 8 + h) * 32 + ts)) * 4096
                           + (c * 64 + e) * 8;
                *(s8v*)dst = ov;
            }
        }
        __syncthreads();
    }
}

// ---------------- main: 256 Q rows/block, 4 waves x 64 rows, fragment reuse --
// LDS-WORK lever: each wave owns 64 Q rows (two 32-row sets qb=0,1); every K/V
// fragment is ds_read ONCE and feeds TWO MFMAs -> LDS-read work per output
// halves (was the largest pipe term, ~44% of the wall).  Grid 256 = 1
// block/CU -> staging DMA per CU also halves.  Ring/vmcnt schedule verbatim
// r5 (best verified).  4 indep MFMA chains per phase (qb x mb) = more ILP.
// XCD-bijective 1-D grid: each XCD owns 32 consecutive work-units.
__global__ __launch_bounds__(256, 1)
void dsattn_main(const float* __restrict__ q, const short* __restrict__ kimg,
                 const short* __restrict__ vimg, const float* __restrict__ tau,
                 float* __restrict__ out)
{
    __shared__ short KV[4][8192];   // per slot: [0..4095] K image, [4096..8191] V image

    const int t    = threadIdx.x;
    const int lane = t & 63;
    const int w    = t >> 6;
    const int l31  = lane & 31;
    const int hi   = lane >> 5;

    // XCD-aware decode: 256 blocks, 32 consecutive work-units per XCD.
    const int hw = blockIdx.x;
    const int wu = (hw & 7) * 32 + (hw >> 3);
    const int mt = wu & 7;          // 8 Q-tiles of 256 rows
    const int h  = (wu >> 3) & 7;
    const int b  = wu >> 6;

    const float scf = 0.125f * 1.44269504088896f * tau[b];  // tau*scale*log2e folded into Q

    // ---- Q B-frags for BOTH 32-row sets: lane holds Q[row][e = 16ks+8hi+j] ----
    s8v qf0[4], qf1[4];
    {
        const float* qb0 = q + ((size_t)b * LL + (size_t)mt * 256 + w * 64 + l31) * RSG
                             + h * EE + 8 * hi;
        #pragma unroll
        for (int ks = 0; ks < 4; ++ks) {
            v4f a0 = *(const v4f*)(qb0 + 16 * ks);
            v4f a1 = *(const v4f*)(qb0 + 16 * ks + 4);
            s4v p0 = pack4bf(a0[0] * scf, a0[1] * scf, a0[2] * scf, a0[3] * scf);
            s4v p1 = pack4bf(a1[0] * scf, a1[1] * scf, a1[2] * scf, a1[3] * scf);
            s8v f;
            #pragma unroll
            for (int j = 0; j < 4; ++j) { f[j] = p0[j]; f[4 + j] = p1[j]; }
            qf0[ks] = f;
        }
        const float* qb1 = qb0 + (size_t)32 * RSG;
        #pragma unroll
        for (int ks = 0; ks < 4; ++ks) {
            v4f a0 = *(const v4f*)(qb1 + 16 * ks);
            v4f a1 = *(const v4f*)(qb1 + 16 * ks + 4);
            s4v p0 = pack4bf(a0[0] * scf, a0[1] * scf, a0[2] * scf, a0[3] * scf);
            s4v p1 = pack4bf(a1[0] * scf, a1[1] * scf, a1[2] * scf, a1[3] * scf);
            s8v f;
            #pragma unroll
            for (int j = 0; j < 4; ++j) { f[j] = p0[j]; f[4 + j] = p1[j]; }
            qf1[ks] = f;
        }
    }

    // ---- staging source: fully linear (K image: waves 0,1; V image: waves 2,3) ----
    const char* gsrc;
    {
        const size_t pan = (size_t)((b * 8 + h) * 32) * 8192;   // 32 tiles x 8KB
        if (w < 2) gsrc = (const char*)kimg + pan + w * 4096 + lane * 16;
        else       gsrc = (const char*)vimg + pan + (w - 2) * 4096 + lane * 16;
    }

    #define STAGE(slot)                                                                   \
        {                                                                                 \
            _Pragma("unroll")                                                             \
            for (int j = 0; j < 4; ++j) {                                                 \
                __builtin_amdgcn_global_load_lds(                                         \
                    (const __attribute__((address_space(1))) unsigned*)(gsrc + j * 1024), \
                    (__attribute__((address_space(3))) unsigned*)&KV[slot][w * 2048 + j * 512], \
                    16, 0, 0);                                                            \
            }                                                                             \
            gsrc += 8192;                                                                 \
        }

    v16f oacc0[2], oacc1[2];
    #pragma unroll
    for (int mb = 0; mb < 2; ++mb)
        #pragma unroll
        for (int r = 0; r < 16; ++r) { oacc0[mb][r] = 0.0f; oacc1[mb][r] = 0.0f; }
    float rsum0 = 0.0f, rsum1 = 0.0f;

    // per-lane fragment offset (shorts): chunk u = (2ks+hi)*64 + mb*32 + l31
    //   -> offset = ks*1024 + mb*256 + rb,  rb = hi*512 + l31*8
    const int rb = hi * 512 + l31 * 8;

    // Drain Q loads so loop vmcnt counts see ONLY staging loads, then fill pipe 3 deep.
    asm volatile("s_waitcnt vmcnt(0)" ::: "memory");
    __builtin_amdgcn_sched_barrier(0);
    STAGE(0);
    STAGE(1);
    STAGE(2);

    #pragma unroll 1
    for (int it = 0; it < 32; ++it) {
        const int p = it & 3;

        // Outstanding before wait: tiles it, it+1, it+2 = 12 loads -> vmcnt(8)
        // retires tile it.  Tail: it=30 -> 8 outstanding -> vmcnt(4); it=31 -> 0.
        __builtin_amdgcn_sched_barrier(0);
        if (it <= 29)      asm volatile("s_waitcnt vmcnt(8)" ::: "memory");
        else if (it == 30) asm volatile("s_waitcnt vmcnt(4)" ::: "memory");
        else               asm volatile("s_waitcnt vmcnt(0)" ::: "memory");
        __builtin_amdgcn_s_barrier();
        __builtin_amdgcn_sched_barrier(0);

        // prefetch tile it+3 into slot (it+3)&3 = (it-1)&3
        if (it <= 28) STAGE((it + 3) & 3);

        const short* Kp = &KV[p][0];
        const short* Vp = &KV[p][4096];

        // ---- S^T = K Q^T : each kf read ONCE, feeds both qb chains ----
        v16f st0[2], st1[2];
        #pragma unroll
        for (int mb = 0; mb < 2; ++mb) {
            v16f z0, z1;
            #pragma unroll
            for (int r = 0; r < 16; ++r) { z0[r] = 0.0f; z1[r] = 0.0f; }
            #pragma unroll
            for (int ks = 0; ks < 4; ++ks) {
                s8v kf = *(const s8v*)&Kp[ks * 1024 + mb * 256 + rb];
                z0 = __builtin_amdgcn_mfma_f32_32x32x16_bf16(kf, qf0[ks], z0, 0, 0, 0);
                z1 = __builtin_amdgcn_mfma_f32_32x32x16_bf16(kf, qf1[ks], z1, 0, 0, 0);
            }
            st0[mb] = z0; st1[mb] = z1;
        }

        // ---- exp2 numerators, row sums, pack P frags (per qb) ----
        s8v pf0[4], pf1[4];
        {
            #pragma unroll
            for (int mb = 0; mb < 2; ++mb)
                #pragma unroll
                for (int r = 0; r < 16; ++r)
                    st0[mb][r] = __builtin_amdgcn_exp2f(st0[mb][r]);
            float s0 = 0.f, s1 = 0.f;
            #pragma unroll
            for (int r = 0; r < 16; ++r) { s0 += st0[0][r]; s1 += st0[1][r]; }
            rsum0 += s0 + s1;
            #pragma unroll
            for (int tt = 0; tt < 4; ++tt) {
                int o = 8 * (tt & 1);
                const v16f& sv = st0[tt >> 1];
                s4v lo = pack4bf(sv[o + 0], sv[o + 1], sv[o + 2], sv[o + 3]);
                s4v hs = pack4bf(sv[o + 4], sv[o + 5], sv[o + 6], sv[o + 7]);
                s8v f;
                #pragma unroll
                for (int j = 0; j < 4; ++j) { f[j] = lo[j]; f[4 + j] = hs[j]; }
                pf0[tt] = f;
            }
        }
        {
            #pragma unroll
            for (int mb = 0; mb < 2; ++mb)
                #pragma unroll
                for (int r = 0; r < 16; ++r)
                    st1[mb][r] = __builtin_amdgcn_exp2f(st1[mb][r]);
            float s0 = 0.f, s1 = 0.f;
            #pragma unroll
            for (int r = 0; r < 16; ++r) { s0 += st1[0][r]; s1 += st1[1][r]; }
            rsum1 += s0 + s1;
            #pragma unroll
            for (int tt = 0; tt < 4; ++tt) {
                int o = 8 * (tt & 1);
                const v16f& sv = st1[tt >> 1];
                s4v lo = pack4bf(sv[o + 0], sv[o + 1], sv[o + 2], sv[o + 3]);
                s4v hs = pack4bf(sv[o + 4], sv[o + 5], sv[o + 6], sv[o + 7]);
                s8v f;
                #pragma unroll
                for (int j = 0; j < 4; ++j) { f[j] = lo[j]; f[4 + j] = hs[j]; }
                pf1[tt] = f;
            }
        }

        // ---- O^T += V^T P^T : each vf read ONCE, feeds both qb chains ----
        #pragma unroll
        for (int mb = 0; mb < 2; ++mb) {
            v16f a0 = oacc0[mb], a1 = oacc1[mb];
            #pragma unroll
            for (int ks = 0; ks < 4; ++ks) {
                s8v vf = *(const s8v*)&Vp[ks * 1024 + mb * 256 + rb];
                a0 = __builtin_amdgcn_mfma_f32_32x32x16_bf16(vf, pf0[ks], a0, 0, 0, 0);
                a1 = __builtin_amdgcn_mfma_f32_32x32x16_bf16(vf, pf1[ks], a1, 0, 0, 0);
            }
            oacc0[mb] = a0; oacc1[mb] = a1;
        }
    }

    // ---- denominators (cross-half reduce) and store O^T -> O (both qb) ----
    rsum0 += __shfl_xor(rsum0, 32);
    rsum1 += __shfl_xor(rsum1, 32);
    const float inv0 = 1.0f / rsum0;
    const float inv1 = 1.0f / rsum1;
    float* ob0 = out + ((size_t)b * LL + (size_t)mt * 256 + w * 64 + l31) * RSG + h * EE;
    float* ob1 = ob0 + (size_t)32 * RSG;
    #pragma unroll
    for (int mb = 0; mb < 2; ++mb)
        #pragma unroll
        for (int rq = 0; rq < 4; ++rq) {
            int e0 = 32 * mb + 8 * rq + 4 * hi;     // C-layout row = (reg&3)+8*(reg>>2)+4*hi
            v4f o4 = { oacc0[mb][4 * rq + 0] * inv0, oacc0[mb][4 * rq + 1] * inv0,
                       oacc0[mb][4 * rq + 2] * inv0, oacc0[mb][4 * rq + 3] * inv0 };
            *(v4f*)(ob0 + e0) = o4;
            v4f o5 = { oacc1[mb][4 * rq + 0] * inv1, oacc1[mb][4 * rq + 1] * inv1,
                       oacc1[mb][4 * rq + 2] * inv1, oacc1[mb][4 * rq + 3] * inv1 };
            *(v4f*)(ob1 + e0) = o5;
        }
}

extern "C" void kernel_launch(void* const* d_in, const int* in_sizes, int n_in,
                              void* d_out, int out_size, void* d_ws, size_t ws_size,
                              hipStream_t stream) {
    const float* q     = (const float*)d_in[0];
    const float* k     = (const float*)d_in[1];
    const float* v     = (const float*)d_in[2];
    // d_in[3] = attn_mask (unused); d_in[5] = delta (drops out of softmax exactly)
    const float* tau   = (const float*)d_in[4];
    float* out = (float*)d_out;

    short* kimg = (short*)d_ws;                   // 4*2048*512 bf16 = 8.39 MB
    short* vimg = kimg + (size_t)4 * SS * RSG;    // 8.39 MB

    dsattn_prep<<<dim3(256), dim3(256), 0, stream>>>(k, v, kimg, vimg);
    dsattn_main<<<dim3(256), dim3(256), 0, stream>>>(q, kimg, vimg, tau, out);
}

// Round 13
// 145.298 us; speedup vs baseline: 1.0198x; 1.0198x over previous
//
#include <hip/hip_runtime.h>
#include <hip/hip_bf16.h>
#include <stdint.h>

#define LL 2048
#define SS 2048
#define HH 8
#define EE 64
#define RSG 512   // global row stride in elements (H*E)

typedef float v4f  __attribute__((ext_vector_type(4)));
typedef float v16f __attribute__((ext_vector_type(16)));
typedef short s4v  __attribute__((ext_vector_type(4)));
typedef short s8v  __attribute__((ext_vector_type(8)));

// fp32 -> bf16 bits, round-to-nearest-even
__device__ __forceinline__ short f2bf(float f) {
    unsigned u = __float_as_uint(f);
    u = (u + 0x7fffu + ((u >> 16) & 1u)) >> 16;
    return (short)u;
}

__device__ __forceinline__ s4v pack4bf(float a, float b, float c, float d) {
    float2 ab = make_float2(a, b), cd = make_float2(c, d);
    __hip_bfloat162 r0 = __float22bfloat162_rn(ab);
    __hip_bfloat162 r1 = __float22bfloat162_rn(cd);
    s4v r;
    __builtin_memcpy(&r, &r0, 4);
    __builtin_memcpy(((char*)&r) + 4, &r1, 4);
    return r;
}

// ---------------- prepass (r11 bandwidth-optimized version, verified) -------
// K image: chunk u = echunk*64 + srow  holds K[srow][8*echunk .. +8) as bf16.
// V image: chunk u = c*64 + e          holds V[perm(c,j)][e], j=0..7, with
//   perm(c,j) = 16*(c>>1) + 4*(c&1) + 8*(j>>2) + (j&3)   (the PV k-permutation)
__global__ __launch_bounds__(256)
void dsattn_prep(const float* __restrict__ kk, const float* __restrict__ vv,
                 short* __restrict__ kimg, short* __restrict__ vimg)
{
    __shared__ short T[32][520];         // 32 rows x 512 bf16 (+8 pad)
    const int t   = threadIdx.x;
    const int blk = blockIdx.x;          // 0..255
    const int isV = blk >> 7;            // 0: K-tensor, 1: V-tensor
    const int b   = (blk & 127) >> 5;
    const int ts  = blk & 31;
    const float* src = (isV ? vv : kk) + ((size_t)b * SS + ts * 64) * RSG;
    short* dimg = isV ? vimg : kimg;

    #pragma unroll 1
    for (int half = 0; half < 2; ++half) {
        const float* hsrc = src + (size_t)(half * 32) * RSG;
        #pragma unroll
        for (int i = 0; i < 16; ++i) {
            int g = i * 256 + t;
            int row = g >> 7, c4 = (g & 127) << 2;
            v4f d = *(const v4f*)(hsrc + (size_t)row * RSG + c4);
            *(s4v*)&T[row][c4] = pack4bf(d[0], d[1], d[2], d[3]);
        }
        __syncthreads();

        if (!isV) {
            const int echunk = t >> 5, srow = t & 31;
            #pragma unroll
            for (int h = 0; h < 8; ++h) {
                s8v ov = *(const s8v*)&T[srow][h * 64 + echunk * 8];
                short* dst = dimg + ((size_t)((b * 8 + h) * 32 + ts)) * 4096
                           + (echunk * 64 + half * 32 + srow) * 8;
                *(s8v*)dst = ov;
            }
        } else {
            const int c = (t >> 6) + half * 4, e = t & 63;
            const int sbase = 16 * (c >> 1) + 4 * (c & 1) - half * 32;
            #pragma unroll
            for (int h = 0; h < 8; ++h) {
                s8v ov;
                #pragma unroll
                for (int j = 0; j < 8; ++j) {
                    int s = sbase + 8 * (j >> 2) + (j & 3);
                    ov[j] = T[s][h * 64 + e];
                }
                short* dst = dimg + ((size_t)((b * 8 + h) * 32 + ts)) * 4096
                           + (c * 64 + e) * 8;
                *(s8v*)dst = ov;
            }
        }
        __syncthreads();
    }
}

// ---------------- main: ZERO-BARRIER per-wave pipelines ----------------------
// 128 Q rows/block, 4 waves x 32 rows — but each wave is a fully independent
// software pipeline: its own 2-slot V ring in LDS (16KB/wave), K fragments
// prefetched one tile ahead into REGISTERS (depth-1, ~900cy cover), per-wave
// counted vmcnt.  No s_barrier anywhere -> waves on a SIMD drift out of phase
// and one wave's MFMA phase fills another's exp/LDS phase (the overlap the
// 32-barriers-per-kernel lockstep of r0-r11 prevented).
// FIFO: at top of tile t, outstanding = V(t)[8, oldest] + {K(t),V(t+1)}[16]
//   -> vmcnt(16) retires exactly V(t); compiler's own waits cover K regs.
// V(t+2) issued into the current slot AFTER PV(t)'s ds_reads (same-wave
// program order + ~500cy DMA latency -> no WAR).
// Fragment math / images / output: verbatim r5/r11 (best verified).
__global__ __launch_bounds__(256, 2)
void dsattn_main(const float* __restrict__ q, const short* __restrict__ kimg,
                 const short* __restrict__ vimg, const float* __restrict__ tau,
                 float* __restrict__ out)
{
    __shared__ short VL[4][2][4096];   // per wave: 2-slot V ring (8KB tiles)

    const int t    = threadIdx.x;
    const int lane = t & 63;
    const int w    = t >> 6;
    const int l31  = lane & 31;
    const int hi   = lane >> 5;

    // XCD-aware decode: 512 blocks, 64 consecutive work-units per XCD.
    const int hw = blockIdx.x;
    const int wu = (hw & 7) * 64 + (hw >> 3);
    const int mt = wu & 15;
    const int h  = (wu >> 4) & 7;
    const int b  = wu >> 7;

    const float scf = 0.125f * 1.44269504088896f * tau[b];  // tau*scale*log2e folded into Q

    // ---- Q B-frags: lane holds Q[w*32+l31][e = 16ks + 8hi + j], pre-scaled ----
    s8v qf[4];
    {
        const float* qb = q + ((size_t)b * LL + (size_t)mt * 128 + w * 32 + l31) * RSG
                            + h * EE + 8 * hi;
        #pragma unroll
        for (int ks = 0; ks < 4; ++ks) {
            v4f a0 = *(const v4f*)(qb + 16 * ks);
            v4f a1 = *(const v4f*)(qb + 16 * ks + 4);
            s4v p0 = pack4bf(a0[0] * scf, a0[1] * scf, a0[2] * scf, a0[3] * scf);
            s4v p1 = pack4bf(a1[0] * scf, a1[1] * scf, a1[2] * scf, a1[3] * scf);
            s8v f;
            #pragma unroll
            for (int j = 0; j < 4; ++j) { f[j] = p0[j]; f[4 + j] = p1[j]; }
            qf[ks] = f;
        }
    }

    const size_t pan = (size_t)((b * 8 + h) * 32) * 8192;   // panel base, bytes

    // K frag source (k-chunk-major image, per-lane): frag (mb,ks) of tile T at
    //   kgp + T*8192 + ks*2048 + mb*512   (lane part folded: hi*1024 + l31*16)
    const char* kgp = (const char*)kimg + pan + hi * 1024 + l31 * 16;

    // V staging source: linear 8KB per tile, per-wave private ring
    const char* gv = (const char*)vimg + pan + lane * 16;

    #define STAGE_V(slot)                                                                 \
        {                                                                                 \
            _Pragma("unroll")                                                             \
            for (int j = 0; j < 8; ++j) {                                                 \
                __builtin_amdgcn_global_load_lds(                                         \
                    (const __attribute__((address_space(1))) unsigned*)(gv + j * 1024),   \
                    (__attribute__((address_space(3))) unsigned*)&VL[w][slot][j * 512],   \
                    16, 0, 0);                                                            \
            }                                                                             \
            gv += 8192;                                                                   \
        }

    s8v kfA[8], kfB[8];      // two K fragment sets (tile t / t+1), f = ks*2 + mb
    #define LOAD_K(dst, tile)                                                             \
        {                                                                                 \
            const char* kp_ = kgp + (size_t)(tile) * 8192;                                \
            _Pragma("unroll")                                                             \
            for (int f = 0; f < 8; ++f)                                                   \
                dst[f] = *(const s8v*)(kp_ + (f >> 1) * 2048 + (f & 1) * 512);            \
        }

    v16f oacc[2];
    #pragma unroll
    for (int mb = 0; mb < 2; ++mb)
        #pragma unroll
        for (int r = 0; r < 16; ++r) oacc[mb][r] = 0.0f;
    float rsum = 0.0f;

    // per-lane V fragment offset (shorts): rb = hi*512 + l31*8
    const int rb = hi * 512 + l31 * 8;

    // Drain qf loads so vmcnt counting sees ONLY pipeline loads; then prologue:
    // V(0) -> slot0, K(0) -> kfA, V(1) -> slot1   (24 outstanding)
    asm volatile("s_waitcnt vmcnt(0)" ::: "memory");
    __builtin_amdgcn_sched_barrier(0);
    STAGE_V(0);
    LOAD_K(kfA, 0);
    STAGE_V(1);

    // one tile of work; K current set KC, next set KN, V in slot SLOT
    #define TILE_BODY(T, SLOT, KC, KN, DO_LDK, DO_STV)                                    \
        {                                                                                 \
            const short* Vp = &VL[w][SLOT][0];                                            \
            /* S^T = K Q^T (K from registers) */                                          \
            v16f st[2];                                                                   \
            _Pragma("unroll")                                                             \
            for (int mb = 0; mb < 2; ++mb) {                                              \
                v16f z;                                                                   \
                _Pragma("unroll")                                                         \
                for (int r = 0; r < 16; ++r) z[r] = 0.0f;                                 \
                _Pragma("unroll")                                                         \
                for (int ks = 0; ks < 4; ++ks)                                            \
                    z = __builtin_amdgcn_mfma_f32_32x32x16_bf16(KC[ks * 2 + mb], qf[ks],  \
                                                                z, 0, 0, 0);              \
                st[mb] = z;                                                               \
            }                                                                             \
            if (DO_LDK) LOAD_K(KN, (T) + 1);       /* K(t+1) issues under exp/pack */     \
            /* exp2 numerator, row sum, pack P frags */                                   \
            _Pragma("unroll")                                                             \
            for (int mb = 0; mb < 2; ++mb)                                                \
                _Pragma("unroll")                                                         \
                for (int r = 0; r < 16; ++r)                                              \
                    st[mb][r] = __builtin_amdgcn_exp2f(st[mb][r]);                        \
            float s0 = 0.f, s1 = 0.f;                                                     \
            _Pragma("unroll")                                                             \
            for (int r = 0; r < 16; ++r) { s0 += st[0][r]; s1 += st[1][r]; }              \
            rsum += s0 + s1;                                                              \
            s8v pf[4];                                                                    \
            _Pragma("unroll")                                                             \
            for (int tt = 0; tt < 4; ++tt) {                                              \
                int o = 8 * (tt & 1);                                                     \
                const v16f& sv = st[tt >> 1];                                             \
                s4v lo = pack4bf(sv[o + 0], sv[o + 1], sv[o + 2], sv[o + 3]);             \
                s4v hs = pack4bf(sv[o + 4], sv[o + 5], sv[o + 6], sv[o + 7]);             \
                s8v f;                                                                    \
                _Pragma("unroll")                                                         \
                for (int j = 0; j < 4; ++j) { f[j] = lo[j]; f[4 + j] = hs[j]; }           \
                pf[tt] = f;                                                               \
            }                                                                             \
            /* O^T += V^T P^T (V from this wave's LDS ring) */                            \
            _Pragma("unroll")                                                             \
            for (int mb = 0; mb < 2; ++mb) {                                              \
                v16f acc = oacc[mb];                                                      \
                _Pragma("unroll")                                                         \
                for (int ks = 0; ks < 4; ++ks) {                                          \
                    s8v vf = *(const s8v*)&Vp[ks * 1024 + mb * 256 + rb];                 \
                    acc = __builtin_amdgcn_mfma_f32_32x32x16_bf16(vf, pf[ks], acc, 0, 0, 0); \
                }                                                                         \
                oacc[mb] = acc;                                                           \
            }                                                                             \
            if (DO_STV) STAGE_V(SLOT);             /* V(t+2), after PV's ds_reads */      \
        }

    #pragma unroll 1
    for (int it = 0; it < 32; it += 2) {
        // ---- even tile t=it: outstanding V(t)+K(t)+V(t+1)=24 -> vmcnt(16) ----
        __builtin_amdgcn_sched_barrier(0);
        asm volatile("s_waitcnt vmcnt(16)" ::: "memory");
        __builtin_amdgcn_sched_barrier(0);
        TILE_BODY(it, 0, kfA, kfB, /*ldk*/ true, /*stv*/ (it <= 29));

        // ---- odd tile t=it+1: t<31 -> vmcnt(16); t=31 -> vmcnt(8) ----
        __builtin_amdgcn_sched_barrier(0);
        if (it + 1 < 31) asm volatile("s_waitcnt vmcnt(16)" ::: "memory");
        else             asm volatile("s_waitcnt vmcnt(8)"  ::: "memory");
        __builtin_amdgcn_sched_barrier(0);
        TILE_BODY(it + 1, 1, kfB, kfA, /*ldk*/ (it <= 29), /*stv*/ (it <= 28));
    }

    // ---- denominator (single cross-half reduce) and store O^T -> O ----
    rsum += __shfl_xor(rsum, 32);
    const float inv = 1.0f / rsum;
    float* ob = out + ((size_t)b * LL + (size_t)mt * 128 + w * 32 + l31) * RSG + h * EE;
    #pragma unroll
    for (int mb = 0; mb < 2; ++mb)
        #pragma unroll
        for (int rq = 0; rq < 4; ++rq) {
            int e0 = 32 * mb + 8 * rq + 4 * hi;     // C-layout row = (reg&3)+8*(reg>>2)+4*hi
            v4f o4 = { oacc[mb][4 * rq + 0] * inv, oacc[mb][4 * rq + 1] * inv,
                       oacc[mb][4 * rq + 2] * inv, oacc[mb][4 * rq + 3] * inv };
            *(v4f*)(ob + e0) = o4;
        }
}

extern "C" void kernel_launch(void* const* d_in, const int* in_sizes, int n_in,
                              void* d_out, int out_size, void* d_ws, size_t ws_size,
                              hipStream_t stream) {
    const float* q     = (const float*)d_in[0];
    const float* k     = (const float*)d_in[1];
    const float* v     = (const float*)d_in[2];
    // d_in[3] = attn_mask (unused); d_in[5] = delta (drops out of softmax exactly)
    const float* tau   = (const float*)d_in[4];
    float* out = (float*)d_out;

    short* kimg = (short*)d_ws;                   // 4*2048*512 bf16 = 8.39 MB
    short* vimg = kimg + (size_t)4 * SS * RSG;    // 8.39 MB

    dsattn_prep<<<dim3(256), dim3(256), 0, stream>>>(k, v, kimg, vimg);
    dsattn_main<<<dim3(512), dim3(256), 0, stream>>>(q, kimg, vimg, tau, out);
}

// Round 14
// 136.868 us; speedup vs baseline: 1.0826x; 1.0616x over previous
//
#include <hip/hip_runtime.h>
#include <hip/hip_bf16.h>
#include <stdint.h>

#define LL 2048
#define SS 2048
#define HH 8
#define EE 64
#define RSG 512   // global row stride in elements (H*E)

typedef float v4f  __attribute__((ext_vector_type(4)));
typedef float v16f __attribute__((ext_vector_type(16)));
typedef short s4v  __attribute__((ext_vector_type(4)));
typedef short s8v  __attribute__((ext_vector_type(8)));

// fp32 -> bf16 bits, round-to-nearest-even
__device__ __forceinline__ short f2bf(float f) {
    unsigned u = __float_as_uint(f);
    u = (u + 0x7fffu + ((u >> 16) & 1u)) >> 16;
    return (short)u;
}

__device__ __forceinline__ s4v pack4bf(float a, float b, float c, float d) {
    float2 ab = make_float2(a, b), cd = make_float2(c, d);
    __hip_bfloat162 r0 = __float22bfloat162_rn(ab);
    __hip_bfloat162 r1 = __float22bfloat162_rn(cd);
    s4v r;
    __builtin_memcpy(&r, &r0, 4);
    __builtin_memcpy(((char*)&r) + 4, &r1, 4);
    return r;
}

// ---------------- prepass (r11 bandwidth-optimized version, verified) -------
// K image: chunk u = echunk*64 + srow  holds K[srow][8*echunk .. +8) as bf16.
// V image: chunk u = c*64 + e          holds V[perm(c,j)][e], j=0..7, with
//   perm(c,j) = 16*(c>>1) + 4*(c&1) + 8*(j>>2) + (j&3)   (the PV k-permutation)
__global__ __launch_bounds__(256)
void dsattn_prep(const float* __restrict__ kk, const float* __restrict__ vv,
                 short* __restrict__ kimg, short* __restrict__ vimg)
{
    __shared__ short T[32][520];         // 32 rows x 512 bf16 (+8 pad)
    const int t   = threadIdx.x;
    const int blk = blockIdx.x;          // 0..255
    const int isV = blk >> 7;            // 0: K-tensor, 1: V-tensor
    const int b   = (blk & 127) >> 5;
    const int ts  = blk & 31;
    const float* src = (isV ? vv : kk) + ((size_t)b * SS + ts * 64) * RSG;
    short* dimg = isV ? vimg : kimg;

    #pragma unroll 1
    for (int half = 0; half < 2; ++half) {
        const float* hsrc = src + (size_t)(half * 32) * RSG;
        #pragma unroll
        for (int i = 0; i < 16; ++i) {
            int g = i * 256 + t;
            int row = g >> 7, c4 = (g & 127) << 2;
            v4f d = *(const v4f*)(hsrc + (size_t)row * RSG + c4);
            *(s4v*)&T[row][c4] = pack4bf(d[0], d[1], d[2], d[3]);
        }
        __syncthreads();

        if (!isV) {
            const int echunk = t >> 5, srow = t & 31;
            #pragma unroll
            for (int h = 0; h < 8; ++h) {
                s8v ov = *(const s8v*)&T[srow][h * 64 + echunk * 8];
                short* dst = dimg + ((size_t)((b * 8 + h) * 32 + ts)) * 4096
                           + (echunk * 64 + half * 32 + srow) * 8;
                *(s8v*)dst = ov;
            }
        } else {
            const int c = (t >> 6) + half * 4, e = t & 63;
            const int sbase = 16 * (c >> 1) + 4 * (c & 1) - half * 32;
            #pragma unroll
            for (int h = 0; h < 8; ++h) {
                s8v ov;
                #pragma unroll
                for (int j = 0; j < 8; ++j) {
                    int s = sbase + 8 * (j >> 2) + (j & 3);
                    ov[j] = T[s][h * 64 + e];
                }
                short* dst = dimg + ((size_t)((b * 8 + h) * 32 + ts)) * 4096
                           + (c * 64 + e) * 8;
                *(s8v*)dst = ov;
            }
        }
        __syncthreads();
    }
}

// ---------------- main: r5/r11 best-verified structure + T5 s_setprio -------
// 128 Q rows/block, 4 waves x 32 rows, all-32x32x16 MFMA.  4-slot LDS ring,
// depth-3 prefetch, counted vmcnt(8) (never 0 in steady state), same-tile
// QK->exp->PV, zero-conflict k-chunk-major images.
// NEW (T5): s_setprio(1) brackets the QK and PV MFMA clusters — waves drift
// slightly between barriers, and priority lets an MFMA-entering wave win
// issue arbitration over co-resident waves in their ds_read/exp phases
// (m191: +4-7% on attn, within-probe verified).
// XCD-bijective 1-D grid: each XCD owns 4 contiguous (b,h) panels.
__global__ __launch_bounds__(256, 2)
void dsattn_main(const float* __restrict__ q, const short* __restrict__ kimg,
                 const short* __restrict__ vimg, const float* __restrict__ tau,
                 float* __restrict__ out)
{
    __shared__ short KV[4][8192];   // per slot: [0..4095] K image, [4096..8191] V image

    const int t    = threadIdx.x;
    const int lane = t & 63;
    const int w    = t >> 6;
    const int l31  = lane & 31;
    const int hi   = lane >> 5;

    // XCD-aware decode: 512 blocks, 8 XCDs, 64 consecutive work-units per XCD.
    const int hw = blockIdx.x;
    const int wu = (hw & 7) * 64 + (hw >> 3);
    const int mt = wu & 15;
    const int h  = (wu >> 4) & 7;
    const int b  = wu >> 7;

    const float scf = 0.125f * 1.44269504088896f * tau[b];  // tau*scale*log2e folded into Q

    // ---- Q B-frags: lane holds Q[w*32+l31][e = 16ks + 8hi + j], pre-scaled ----
    s8v qf[4];
    {
        const float* qb = q + ((size_t)b * LL + (size_t)mt * 128 + w * 32 + l31) * RSG
                            + h * EE + 8 * hi;
        #pragma unroll
        for (int ks = 0; ks < 4; ++ks) {
            v4f a0 = *(const v4f*)(qb + 16 * ks);
            v4f a1 = *(const v4f*)(qb + 16 * ks + 4);
            s4v p0 = pack4bf(a0[0] * scf, a0[1] * scf, a0[2] * scf, a0[3] * scf);
            s4v p1 = pack4bf(a1[0] * scf, a1[1] * scf, a1[2] * scf, a1[3] * scf);
            s8v f;
            #pragma unroll
            for (int j = 0; j < 4; ++j) { f[j] = p0[j]; f[4 + j] = p1[j]; }
            qf[ks] = f;
        }
    }

    // ---- staging source: fully linear (K image: waves 0,1; V image: waves 2,3) ----
    const char* gsrc;
    {
        const size_t pan = (size_t)((b * 8 + h) * 32) * 8192;   // 32 tiles x 8KB
        if (w < 2) gsrc = (const char*)kimg + pan + w * 4096 + lane * 16;
        else       gsrc = (const char*)vimg + pan + (w - 2) * 4096 + lane * 16;
    }

    #define STAGE(slot)                                                                   \
        {                                                                                 \
            _Pragma("unroll")                                                             \
            for (int j = 0; j < 4; ++j) {                                                 \
                __builtin_amdgcn_global_load_lds(                                         \
                    (const __attribute__((address_space(1))) unsigned*)(gsrc + j * 1024), \
                    (__attribute__((address_space(3))) unsigned*)&KV[slot][w * 2048 + j * 512], \
                    16, 0, 0);                                                            \
            }                                                                             \
            gsrc += 8192;                                                                 \
        }

    v16f oacc[2];
    #pragma unroll
    for (int mb = 0; mb < 2; ++mb)
        #pragma unroll
        for (int r = 0; r < 16; ++r) oacc[mb][r] = 0.0f;
    float rsum = 0.0f;

    // per-lane fragment offset (shorts): chunk u = (2ks+hi)*64 + mb*32 + l31
    //   -> offset = ks*1024 + mb*256 + rb,  rb = hi*512 + l31*8
    const int rb = hi * 512 + l31 * 8;

    // Drain Q loads so loop vmcnt counts see ONLY staging loads, then fill pipe 3 deep.
    asm volatile("s_waitcnt vmcnt(0)" ::: "memory");
    __builtin_amdgcn_sched_barrier(0);
    STAGE(0);
    STAGE(1);
    STAGE(2);

    #pragma unroll 4
    for (int it = 0; it < 32; ++it) {
        const int p = it & 3;

        // Outstanding before wait: tiles it, it+1, it+2 = 12 loads -> vmcnt(8)
        // retires tile it.  Tail: it=30 -> 8 outstanding -> vmcnt(4); it=31 -> 0.
        __builtin_amdgcn_sched_barrier(0);
        if (it <= 29)      asm volatile("s_waitcnt vmcnt(8)" ::: "memory");
        else if (it == 30) asm volatile("s_waitcnt vmcnt(4)" ::: "memory");
        else               asm volatile("s_waitcnt vmcnt(0)" ::: "memory");
        __builtin_amdgcn_s_barrier();
        __builtin_amdgcn_sched_barrier(0);

        // prefetch tile it+3 into slot (it+3)&3 = (it-1)&3 (its readers finished
        // during iter it-1; all waves passed the barrier above since)
        if (it <= 28) STAGE((it + 3) & 3);

        const short* Kp = &KV[p][0];
        const short* Vp = &KV[p][4096];

        // ---- S^T = K Q^T : 2 s-row-blocks x 4 k-steps (setprio-bracketed) ----
        v16f st[2];
        __builtin_amdgcn_s_setprio(1);
        #pragma unroll
        for (int mb = 0; mb < 2; ++mb) {
            v16f z;
            #pragma unroll
            for (int r = 0; r < 16; ++r) z[r] = 0.0f;
            #pragma unroll
            for (int ks = 0; ks < 4; ++ks) {
                s8v kf = *(const s8v*)&Kp[ks * 1024 + mb * 256 + rb];
                z = __builtin_amdgcn_mfma_f32_32x32x16_bf16(kf, qf[ks], z, 0, 0, 0);
            }
            st[mb] = z;
        }
        __builtin_amdgcn_s_setprio(0);

        // ---- exp2 numerator (tau pre-folded, no max-tracking), row sum, pack P frags ----
        #pragma unroll
        for (int mb = 0; mb < 2; ++mb)
            #pragma unroll
            for (int r = 0; r < 16; ++r)
                st[mb][r] = __builtin_amdgcn_exp2f(st[mb][r]);
        float s0 = 0.f, s1 = 0.f;
        #pragma unroll
        for (int r = 0; r < 16; ++r) { s0 += st[0][r]; s1 += st[1][r]; }
        rsum += s0 + s1;

        s8v pf[4];    // B-operand for PV, straight from C-layout registers
        #pragma unroll
        for (int tt = 0; tt < 4; ++tt) {
            int o = 8 * (tt & 1);
            const v16f& sv = st[tt >> 1];
            s4v lo = pack4bf(sv[o + 0], sv[o + 1], sv[o + 2], sv[o + 3]);
            s4v hs = pack4bf(sv[o + 4], sv[o + 5], sv[o + 6], sv[o + 7]);
            s8v f;
            #pragma unroll
            for (int j = 0; j < 4; ++j) { f[j] = lo[j]; f[4 + j] = hs[j]; }
            pf[tt] = f;
        }

        // ---- O^T += V^T P^T : 2 e-row-blocks x 4 k-steps (setprio-bracketed) ----
        __builtin_amdgcn_s_setprio(1);
        #pragma unroll
        for (int mb = 0; mb < 2; ++mb) {
            v16f acc = oacc[mb];
            #pragma unroll
            for (int ks = 0; ks < 4; ++ks) {
                s8v vf = *(const s8v*)&Vp[ks * 1024 + mb * 256 + rb];
                acc = __builtin_amdgcn_mfma_f32_32x32x16_bf16(vf, pf[ks], acc, 0, 0, 0);
            }
            oacc[mb] = acc;
        }
        __builtin_amdgcn_s_setprio(0);
    }

    // ---- denominator (single cross-half reduce) and store O^T -> O ----
    rsum += __shfl_xor(rsum, 32);
    const float inv = 1.0f / rsum;
    float* ob = out + ((size_t)b * LL + (size_t)mt * 128 + w * 32 + l31) * RSG + h * EE;
    #pragma unroll
    for (int mb = 0; mb < 2; ++mb)
        #pragma unroll
        for (int rq = 0; rq < 4; ++rq) {
            int e0 = 32 * mb + 8 * rq + 4 * hi;     // C-layout row = (reg&3)+8*(reg>>2)+4*hi
            v4f o4 = { oacc[mb][4 * rq + 0] * inv, oacc[mb][4 * rq + 1] * inv,
                       oacc[mb][4 * rq + 2] * inv, oacc[mb][4 * rq + 3] * inv };
            *(v4f*)(ob + e0) = o4;
        }
}

extern "C" void kernel_launch(void* const* d_in, const int* in_sizes, int n_in,
                              void* d_out, int out_size, void* d_ws, size_t ws_size,
                              hipStream_t stream) {
    const float* q     = (const float*)d_in[0];
    const float* k     = (const float*)d_in[1];
    const float* v     = (const float*)d_in[2];
    // d_in[3] = attn_mask (unused); d_in[5] = delta (drops out of softmax exactly)
    const float* tau   = (const float*)d_in[4];
    float* out = (float*)d_out;

    short* kimg = (short*)d_ws;                   // 4*2048*512 bf16 = 8.39 MB
    short* vimg = kimg + (size_t)4 * SS * RSG;    // 8.39 MB

    dsattn_prep<<<dim3(256), dim3(256), 0, stream>>>(k, v, kimg, vimg);
    dsattn_main<<<dim3(512), dim3(256), 0, stream>>>(q, kimg, vimg, tau, out);
}